// Round 19
// baseline (118.843 us; speedup 1.0000x reference)
//
#include <hip/hip_runtime.h>
#include <hip/hip_bf16.h>
#include <stdint.h>

// GraphUnet forward, N=4096, D=128, E=131072, K=2457.
// 6 dispatches: zero||W2||cu | h0+score+tall||build_bits | rank||scan |
// sub||scatter||tT-gather | gemm->uu | agg.
// R19: k_t's GEMM moved into h0_build (tall = (h0*score)@W2 for ALL rows,
// computed by the blocks that already hold h0+score in registers, hidden
// under build_bits); dispatch 4 only gathers tall[idxl] -> bf16 tT.
// W2/cu precompute moved to dispatch 1 (input-only). invdeg stays folded
// into gemm A-side (R18, absmax-verified).

#define NN 4096
#define DD 128
#define KKEEP 2457              // int(0.6*4096)
#define SUBW 40                 // ceil(KKEEP/64)
#define MP 2464                 // KKEEP padded to 16
#define KP 2560                 // KKEEP padded to SUBW*64
#define MT 154
#define NT 8
#define KCHUNK (KP / 4)         // 640 per wave in gemm
#define RT 8

typedef unsigned long long u64;
typedef unsigned short ushort_t;
typedef __attribute__((ext_vector_type(8))) short bf16x8;
typedef __attribute__((ext_vector_type(4))) float f32x4;

// blocks [0,1040): zero rowbits+deg+cursor | [1040,1056): W2=Wb@Wu | 1056: cu=bb@Wu
__global__ void k_zero_w2(float4* __restrict__ zbase, const float* __restrict__ Wb,
                          const float* __restrict__ Wu, const float* __restrict__ bb,
                          float* __restrict__ W2, float* __restrict__ cu) {
    __shared__ float rows[RT][DD];
    int bid = blockIdx.x, d = threadIdx.x;
    if (bid < 1040) {
        zbase[bid * 128 + d] = make_float4(0.f, 0.f, 0.f, 0.f);
        return;
    }
    if (bid < 1056) {
        int r0 = (bid - 1040) * RT;
        #pragma unroll
        for (int r = 0; r < RT; ++r) rows[r][d] = Wb[(size_t)(r0 + r) * DD + d];
        __syncthreads();
        float acc[RT];
        #pragma unroll
        for (int r = 0; r < RT; ++r) acc[r] = 0.f;
        for (int kb = 0; kb < DD; kb += 16) {
            float w[16];
            #pragma unroll
            for (int j = 0; j < 16; ++j) w[j] = Wu[(size_t)(kb + j) * DD + d];
            #pragma unroll
            for (int r = 0; r < RT; ++r)
                #pragma unroll
                for (int j = 0; j < 16; ++j) acc[r] += rows[r][kb + j] * w[j];
        }
        #pragma unroll
        for (int r = 0; r < RT; ++r) W2[(size_t)(r0 + r) * DD + d] = acc[r];
        return;
    }
    float a = 0.f;
    for (int m = 0; m < DD; ++m) a += bb[m] * Wu[(size_t)m * DD + d];
    cu[d] = a;
}

// blocks [0,512): h0 + score + tall=(h0*score)@W2 | [512,1536): build_bits
__global__ void k_h0_build(const float* __restrict__ h, const float* __restrict__ Wd,
                           const float* __restrict__ bd, const float* __restrict__ pw,
                           const float* __restrict__ pb, const int* __restrict__ g, int E,
                           const float* __restrict__ W2,
                           float* __restrict__ h0, float* __restrict__ scores,
                           float* __restrict__ tall,
                           u64* __restrict__ rowbits, int* __restrict__ deg) {
    __shared__ float rows[RT][DD];
    __shared__ float sred[2][RT];
    int bid = blockIdx.x;
    int d = threadIdx.x;
    if (bid >= 512) {
        int e = (bid - 512) * 128 + d;
        if (e < E) {
            int s = g[e], d2 = g[E + e];
            atomicOr(&rowbits[(size_t)s * 64 + (d2 >> 6)], 1ull << (d2 & 63));
            atomicAdd(&deg[s], 1);
        }
        return;
    }
    int r0 = bid * RT;
    #pragma unroll
    for (int r = 0; r < RT; ++r) rows[r][d] = h[(size_t)(r0 + r) * DD + d];
    __syncthreads();
    float acc[RT];
    float b = bd[d];
    #pragma unroll
    for (int r = 0; r < RT; ++r) acc[r] = b;
    for (int kb = 0; kb < DD; kb += 16) {
        float w[16];
        #pragma unroll
        for (int j = 0; j < 16; ++j) w[j] = Wd[(size_t)(kb + j) * DD + d];
        #pragma unroll
        for (int r = 0; r < RT; ++r)
            #pragma unroll
            for (int j = 0; j < 16; ++j) acc[r] += rows[r][kb + j] * w[j];
    }
    #pragma unroll
    for (int r = 0; r < RT; ++r) h0[(size_t)(r0 + r) * DD + d] = acc[r];
    float pwd = pw[d];
    float pb0 = pb[0];
    int lane = d & 63, wv = d >> 6;
    #pragma unroll
    for (int r = 0; r < RT; ++r) {
        float v = acc[r] * pwd;
        #pragma unroll
        for (int s = 32; s > 0; s >>= 1) v += __shfl_xor(v, s);
        if (lane == 0) sred[wv][r] = v;
    }
    __syncthreads();
    if (d < RT) {
        float v = sred[0][d] + sred[1][d];
        scores[r0 + d] = 1.0f / (1.0f + expf(-(v + pb0)));
    }
    // tall section: newh rows (h0*score) back into LDS, then @ W2
    float sc[RT];
    #pragma unroll
    for (int r = 0; r < RT; ++r)
        sc[r] = 1.0f / (1.0f + expf(-(sred[0][r] + sred[1][r] + pb0)));
    #pragma unroll
    for (int r = 0; r < RT; ++r) rows[r][d] = acc[r] * sc[r];
    __syncthreads();
    float acc2[RT];
    #pragma unroll
    for (int r = 0; r < RT; ++r) acc2[r] = 0.f;
    for (int kb = 0; kb < DD; kb += 16) {
        float w[16];
        #pragma unroll
        for (int j = 0; j < 16; ++j) w[j] = W2[(size_t)(kb + j) * DD + d];
        #pragma unroll
        for (int r = 0; r < RT; ++r)
            #pragma unroll
            for (int j = 0; j < 16; ++j) acc2[r] += rows[r][kb + j] * w[j];
    }
    #pragma unroll
    for (int r = 0; r < RT; ++r) tall[(size_t)(r0 + r) * DD + d] = acc2[r];
}

__global__ void k_rank_scan(const float* __restrict__ scores, const int* __restrict__ deg,
                            int* __restrict__ keep, int* __restrict__ pos,
                            int* __restrict__ idxl, int* __restrict__ off) {
    int bid = blockIdx.x;
    int t = threadIdx.x;
    if (bid == NN / 4) {
        __shared__ int part[256];
        int base = t * 16;
        int loc[16]; int s = 0;
        #pragma unroll
        for (int i = 0; i < 16; ++i) { loc[i] = s; s += deg[base + i]; }
        part[t] = s;
        __syncthreads();
        int sum = 0;
        for (int i = 0; i < t; ++i) sum += part[i];
        #pragma unroll
        for (int i = 0; i < 16; ++i) off[base + i] = sum + loc[i];
        if (t == 255) off[NN] = sum + s;
        return;
    }
    int lane = t & 63;
    int i = bid * 4 + (t >> 6);
    float my = scores[i];
    int rank = 0;
    #pragma unroll 4
    for (int base = 0; base < NN; base += 64) {
        int jj = base + lane;
        float sj = scores[jj];
        u64 m = __ballot((sj > my) || (sj == my && jj < i));
        rank += __popcll(m);
    }
    if (lane == 0) {
        if (rank < KKEEP) { keep[i] = 1; pos[i] = rank; idxl[rank] = i; }
        else keep[i] = 0;
    }
}

// blocks [0,MP): sub -> subbits + invdegb(bf16)
// blocks [MP,MP+512): csrv scatter
// blocks [MP+512,MP+512+160): tT gather: tT[d][c] = bf16(tall[idxl[c]][d])
__global__ void k_sub_scatter_g(const u64* __restrict__ rowbits, const int* __restrict__ idxl,
                                const int* __restrict__ g, int E, const int* __restrict__ off,
                                const int* __restrict__ keep, const int* __restrict__ pos,
                                int* __restrict__ cursor, int* __restrict__ csrv,
                                u64* __restrict__ subbits, ushort_t* __restrict__ invdegb,
                                const float* __restrict__ tall, ushort_t* __restrict__ tT) {
    __shared__ int nb[320];
    __shared__ int nbcnt;
    __shared__ int cntS;
    __shared__ u64 accLDS[64];
    int bid = blockIdx.x;
    int t = threadIdx.x;
    if (bid >= MP + 512) {
        // gather: 16 cols per block, two 8-col halves
        int u = bid - (MP + 512);
        int half = t >> 7, d = t & 127;
        int c0 = u * 16 + half * 8;
        bf16x8 packed;
        #pragma unroll
        for (int r = 0; r < 8; ++r) {
            int cc = c0 + r;
            float v = 0.f;
            if (cc < KKEEP) v = tall[(size_t)idxl[cc] * DD + d];
            __hip_bfloat16 b = __float2bfloat16(v);
            packed[r] = *reinterpret_cast<short*>(&b);
        }
        *reinterpret_cast<bf16x8*>(tT + (size_t)d * KP + c0) = packed;
        return;
    }
    if (bid >= MP) {
        int e = (bid - MP) * 256 + t;
        if (e < E) {
            int s = g[e], dd = g[E + e];
            int p = atomicAdd(&cursor[s], 1);
            csrv[off[s] + p] = keep[dd] ? pos[dd] : -1;
        }
        return;
    }
    int r = bid;
    int wv = t >> 6, lane = t & 63;
    if (r >= KKEEP) {
        if (t < SUBW) subbits[(size_t)r * SUBW + t] = 0;
        return;
    }
    int i = idxl[r];
    if (wv == 0) {
        u64 rw = rowbits[(size_t)i * 64 + lane];
        int myc = __popcll(rw);
        int pre = myc;
        #pragma unroll
        for (int s2 = 1; s2 < 64; s2 <<= 1) {
            int tt = __shfl_up(pre, s2);
            if (lane >= s2) pre += tt;
        }
        pre -= myc;
        u64 w = rw; int j = 0;
        while (w) {
            int b = __builtin_ctzll(w);
            w &= w - 1;
            nb[pre + j] = lane * 64 + b; ++j;
        }
        if (lane == 63) nbcnt = pre + myc;
    } else if (wv == 1) {
        accLDS[lane] = 0;
    } else if (wv == 2 && lane == 0) {
        cntS = 0;
    }
    __syncthreads();
    int cnt_nb = nbcnt;
    u64 accw = 0;
    for (int j = wv; j < cnt_nb; j += 4)
        accw |= rowbits[(size_t)nb[j] * 64 + lane];
    atomicOr(&accLDS[lane], accw);
    __syncthreads();
    u64 accw_full = accLDS[lane];
    int cntp = 0;
    #pragma unroll
    for (int wjj = 0; wjj < 10; ++wjj) {
        int wj = wv * 10 + wjj;
        int c = wj * 64 + lane;
        int ci = (c < KKEEP) ? idxl[c] : 0;
        u64 w = __shfl(accw_full, ci >> 6);
        int bit = (c < KKEEP) ? (int)((w >> (ci & 63)) & 1ull) : 0;
        u64 word = __ballot(bit);
        cntp += __popcll(word);
        if (lane == 0) subbits[(size_t)r * SUBW + wj] = word;
    }
    if (lane == 0) atomicAdd(&cntS, cntp);
    __syncthreads();
    if (t == 0) {
        __hip_bfloat16 b = __float2bfloat16(1.0f / (float)cntS);
        invdegb[r] = *reinterpret_cast<ushort_t*>(&b);
    }
}

// uu = (S*invdeg) @ t' + cu: A-fragment = invdegb[k] AND-masked by bits.
__global__ void k_gemm(const u64* __restrict__ subbits, const ushort_t* __restrict__ invdegb,
                       const short* __restrict__ tT, const float* __restrict__ cu,
                       float* __restrict__ uu) {
    __shared__ f32x4 red[4][64];
    __shared__ uint4 lut[256];
    int t = threadIdx.x;
    {   // byte -> 4 u32 of 0xFFFF masks per set bit
        uint32_t m0 = ((t & 1) ? 0xFFFFu : 0u) | ((t & 2) ? 0xFFFF0000u : 0u);
        uint32_t m1 = ((t & 4) ? 0xFFFFu : 0u) | ((t & 8) ? 0xFFFF0000u : 0u);
        uint32_t m2 = ((t & 16) ? 0xFFFFu : 0u) | ((t & 32) ? 0xFFFF0000u : 0u);
        uint32_t m3 = ((t & 64) ? 0xFFFFu : 0u) | ((t & 128) ? 0xFFFF0000u : 0u);
        lut[t] = make_uint4(m0, m1, m2, m3);
    }
    __syncthreads();
    int bid = blockIdx.x;
    int tile = (bid & 7) * (MT * NT / 8) + (bid >> 3);   // bijective: 1232=8*154
    int wv = t >> 6, lane = t & 63;
    int rt = tile >> 3, ct = tile & 7;
    const u64* abits = subbits + (size_t)(rt * 16 + (lane & 15)) * SUBW;
    const short* brow = tT + (size_t)(ct * 16 + (lane & 15)) * KP + ((lane >> 4) * 8) + wv * KCHUNK;
    int kbase = wv * KCHUNK + ((lane >> 4) * 8);
    f32x4 acc = {0.f, 0.f, 0.f, 0.f};
    #pragma unroll 4
    for (int kk = 0; kk < KCHUNK; kk += 32) {
        int k = kbase + kk;
        u64 w = abits[k >> 6];
        int byte = (int)((w >> (k & 63)) & 0xFFull);
        uint4 msk = lut[byte];
        uint4 ivb = *(const uint4*)(invdegb + k);
        uint4 af = make_uint4(msk.x & ivb.x, msk.y & ivb.y, msk.z & ivb.z, msk.w & ivb.w);
        bf16x8 a = *reinterpret_cast<bf16x8*>(&af);
        bf16x8 b = *(const bf16x8*)(brow + kk);
        acc = __builtin_amdgcn_mfma_f32_16x16x32_bf16(a, b, acc, 0, 0, 0);
    }
    red[wv][lane] = acc;
    __syncthreads();
    if (wv == 0) {
        f32x4 s = red[0][lane] + red[1][lane] + red[2][lane] + red[3][lane];
        int col = ct * 16 + (lane & 15);
        float cuv = cu[col];
        int row0 = rt * 16 + ((lane >> 4) * 4);
        #pragma unroll
        for (int j = 0; j < 4; ++j) {
            int row = row0 + j;
            if (row < KKEEP) uu[(size_t)row * DD + col] = s[j] + cuv;
        }
    }
}

__global__ void k_agg(const int* __restrict__ off, const int* __restrict__ csrv,
                      const float* __restrict__ uu, const float* __restrict__ bu,
                      const float* __restrict__ h0, const float* __restrict__ h,
                      float* __restrict__ out) {
    int s = blockIdx.x, d = threadIdx.x;
    int b = off[s], e2 = off[s + 1];
    float acc = 0.f;
    int k = b;
    for (; k + 4 <= e2; k += 4) {
        int v0 = csrv[k], v1 = csrv[k + 1], v2 = csrv[k + 2], v3 = csrv[k + 3];
        float a0 = (v0 >= 0) ? uu[(size_t)v0 * DD + d] : 0.f;
        float a1 = (v1 >= 0) ? uu[(size_t)v1 * DD + d] : 0.f;
        float a2 = (v2 >= 0) ? uu[(size_t)v2 * DD + d] : 0.f;
        float a3 = (v3 >= 0) ? uu[(size_t)v3 * DD + d] : 0.f;
        acc += (a0 + a1) + (a2 + a3);
    }
    for (; k < e2; ++k) {
        int v = csrv[k];
        if (v >= 0) acc += uu[(size_t)v * DD + d];
    }
    size_t o = (size_t)s * DD + d;
    float a = acc + bu[d] + h0[o];
    out[o] = a;
    out[(size_t)NN * DD + o] = a + h[o];
}

extern "C" void kernel_launch(void* const* d_in, const int* in_sizes, int n_in,
                              void* d_out, int out_size, void* d_ws, size_t ws_size,
                              hipStream_t stream) {
    const int*   g  = (const int*)d_in[0];
    const float* h  = (const float*)d_in[1];
    const float* Wd = (const float*)d_in[2];
    const float* bd = (const float*)d_in[3];
    const float* pw = (const float*)d_in[4];
    const float* pb = (const float*)d_in[5];
    const float* Wb = (const float*)d_in[6];
    const float* bb = (const float*)d_in[7];
    const float* Wu = (const float*)d_in[8];
    const float* bu = (const float*)d_in[9];
    float* out = (float*)d_out;
    int E = in_sizes[0] / 2;

    char* ws = (char*)d_ws;
    u64*      subbits = (u64*)  (ws + 0);                  // 788 KB
    u64*      rowbits = (u64*)  (ws + (13u << 20));        // 2 MB
    int*      deg     = (int*)  (ws + (15u << 20));        // 16 KB
    int*      cursor  = (int*)  (ws + (15u << 20) + 16384);
    int*      off     = (int*)  (ws + (15u << 20) + 32768);
    float*    h0      = (float*)(ws + (16u << 20));        // 2 MB
    ushort_t* tT      = (ushort_t*)(ws + (18u << 20));     // 656 KB
    int*      csrv    = (int*)  (ws + (21u << 20));        // 512 KB
    float*    uu      = (float*)(ws + (22u << 20));        // 1.26 MB
    float*    scores  = (float*)(ws + (24u << 20));
    ushort_t* invdegb = (ushort_t*)(ws + (24u << 20) + 16384);
    int*      pos     = (int*)  (ws + (24u << 20) + 32768);
    int*      keep    = (int*)  (ws + (24u << 20) + 49152);
    int*      idxl    = (int*)  (ws + (24u << 20) + 65536);
    float*    W2      = (float*)(ws + (24u << 20) + 98304); // 64 KB
    float*    cu      = (float*)(ws + (24u << 20) + 98304 + 65536);
    float*    tall    = (float*)(ws + (26u << 20));        // 2 MB

    k_zero_w2<<<1057, 128, 0, stream>>>((float4*)rowbits, Wb, Wu, bb, W2, cu);
    k_h0_build<<<1536, 128, 0, stream>>>(h, Wd, bd, pw, pb, g, E, W2,
                                         h0, scores, tall, rowbits, deg);
    k_rank_scan<<<NN / 4 + 1, 256, 0, stream>>>(scores, deg, keep, pos, idxl, off);
    k_sub_scatter_g<<<MP + 512 + 160, 256, 0, stream>>>(rowbits, idxl, g, E, off,
                                                        keep, pos, cursor, csrv,
                                                        subbits, invdegb, tall, tT);
    k_gemm<<<MT * NT, 256, 0, stream>>>(subbits, invdegb, (const short*)tT, cu, uu);
    k_agg<<<NN, DD, 0, stream>>>(off, csrv, uu, bu, h0, h, out);
}

// Round 20
// 107.631 us; speedup vs baseline: 1.1042x; 1.1042x over previous
//
#include <hip/hip_runtime.h>
#include <hip/hip_bf16.h>
#include <stdint.h>

// GraphUnet forward, N=4096, D=128, E=131072, K=2457.
// R20 = exact revert to R17 (best measured: 108.0 us, absmax 0.015625).
// 7 dispatches: zero | h0+score||build_bits||W2||cu | rank||scan |
// sub||scatter | t | gemm->uu | agg.
// Bitset-S (u64 subbits, 788KB) + byte->LUT A-expansion in gemm;
// pre-scaled t' (invdeg on t rows); standalone k_t RT=8 (proven shape).
// History: R18 invdeg-fold+fusion +2.2us; R19 tall-in-h0 +8.6us — both
// reverted. R15 RT2=4 k_t split was -44us regression. Cooperative mega
// kernel was 4x worse (R13).

#define NN 4096
#define DD 128
#define KKEEP 2457              // int(0.6*4096)
#define SUBW 40                 // ceil(KKEEP/64)
#define MP 2464                 // KKEEP padded to 16
#define KP 2560                 // KKEEP padded to SUBW*64
#define MT 154
#define NT 8
#define KCHUNK (KP / 4)         // 640 per wave in gemm
#define RT 8

typedef unsigned long long u64;
typedef unsigned short ushort_t;
typedef __attribute__((ext_vector_type(8))) short bf16x8;
typedef __attribute__((ext_vector_type(4))) float f32x4;

__global__ void k_zero(float4* __restrict__ p) {
    int i = blockIdx.x * 256 + threadIdx.x;
    p[i] = make_float4(0.f, 0.f, 0.f, 0.f);
}

// blocks [0,512): h0+score | [512,1536): build_bits | [1536,1552): W2 | 1552: cu
__global__ void k_h0_build(const float* __restrict__ h, const float* __restrict__ Wd,
                           const float* __restrict__ bd, const float* __restrict__ pw,
                           const float* __restrict__ pb, const int* __restrict__ g, int E,
                           const float* __restrict__ Wb, const float* __restrict__ Wu,
                           const float* __restrict__ bb,
                           float* __restrict__ h0, float* __restrict__ scores,
                           u64* __restrict__ rowbits, int* __restrict__ deg,
                           float* __restrict__ W2, float* __restrict__ cu) {
    __shared__ float rows[RT][DD];
    __shared__ float sred[2][RT];
    int bid = blockIdx.x;
    int d = threadIdx.x;
    if (bid >= 1536) {
        int wb = bid - 1536;
        if (wb < 16) {
            int r0 = wb * RT;
            #pragma unroll
            for (int r = 0; r < RT; ++r) rows[r][d] = Wb[(size_t)(r0 + r) * DD + d];
            __syncthreads();
            float acc[RT];
            #pragma unroll
            for (int r = 0; r < RT; ++r) acc[r] = 0.f;
            for (int kb = 0; kb < DD; kb += 16) {
                float w[16];
                #pragma unroll
                for (int j = 0; j < 16; ++j) w[j] = Wu[(size_t)(kb + j) * DD + d];
                #pragma unroll
                for (int r = 0; r < RT; ++r)
                    #pragma unroll
                    for (int j = 0; j < 16; ++j) acc[r] += rows[r][kb + j] * w[j];
            }
            #pragma unroll
            for (int r = 0; r < RT; ++r) W2[(size_t)(r0 + r) * DD + d] = acc[r];
        } else {
            float a = 0.f;
            for (int m = 0; m < DD; ++m) a += bb[m] * Wu[(size_t)m * DD + d];
            cu[d] = a;
        }
        return;
    }
    if (bid >= 512) {
        int e = (bid - 512) * 128 + d;
        if (e < E) {
            int s = g[e], d2 = g[E + e];
            atomicOr(&rowbits[(size_t)s * 64 + (d2 >> 6)], 1ull << (d2 & 63));
            atomicAdd(&deg[s], 1);
        }
        return;
    }
    int r0 = bid * RT;
    #pragma unroll
    for (int r = 0; r < RT; ++r) rows[r][d] = h[(size_t)(r0 + r) * DD + d];
    __syncthreads();
    float acc[RT];
    float b = bd[d];
    #pragma unroll
    for (int r = 0; r < RT; ++r) acc[r] = b;
    for (int kb = 0; kb < DD; kb += 16) {
        float w[16];
        #pragma unroll
        for (int j = 0; j < 16; ++j) w[j] = Wd[(size_t)(kb + j) * DD + d];
        #pragma unroll
        for (int r = 0; r < RT; ++r)
            #pragma unroll
            for (int j = 0; j < 16; ++j) acc[r] += rows[r][kb + j] * w[j];
    }
    #pragma unroll
    for (int r = 0; r < RT; ++r) h0[(size_t)(r0 + r) * DD + d] = acc[r];
    float pwd = pw[d];
    int lane = d & 63, wv = d >> 6;
    #pragma unroll
    for (int r = 0; r < RT; ++r) {
        float v = acc[r] * pwd;
        #pragma unroll
        for (int s = 32; s > 0; s >>= 1) v += __shfl_xor(v, s);
        if (lane == 0) sred[wv][r] = v;
    }
    __syncthreads();
    if (d < RT) {
        float v = sred[0][d] + sred[1][d];
        scores[r0 + d] = 1.0f / (1.0f + expf(-(v + pb[0])));
    }
}

__global__ void k_rank_scan(const float* __restrict__ scores, const int* __restrict__ deg,
                            int* __restrict__ keep, int* __restrict__ pos,
                            int* __restrict__ idxl, int* __restrict__ off) {
    int bid = blockIdx.x;
    int t = threadIdx.x;
    if (bid == NN / 4) {
        __shared__ int part[256];
        int base = t * 16;
        int loc[16]; int s = 0;
        #pragma unroll
        for (int i = 0; i < 16; ++i) { loc[i] = s; s += deg[base + i]; }
        part[t] = s;
        __syncthreads();
        int sum = 0;
        for (int i = 0; i < t; ++i) sum += part[i];
        #pragma unroll
        for (int i = 0; i < 16; ++i) off[base + i] = sum + loc[i];
        if (t == 255) off[NN] = sum + s;
        return;
    }
    int lane = t & 63;
    int i = bid * 4 + (t >> 6);
    float my = scores[i];
    int rank = 0;
    #pragma unroll 4
    for (int base = 0; base < NN; base += 64) {
        int jj = base + lane;
        float sj = scores[jj];
        u64 m = __ballot((sj > my) || (sj == my && jj < i));
        rank += __popcll(m);
    }
    if (lane == 0) {
        if (rank < KKEEP) { keep[i] = 1; pos[i] = rank; idxl[rank] = i; }
        else keep[i] = 0;
    }
}

// blocks [0,MP): 2-hop row r -> subbits (u64 bitset) + invdeg;
// blocks [MP, MP+512): csrv scatter.
__global__ void k_sub_scatter(const u64* __restrict__ rowbits, const int* __restrict__ idxl,
                              const int* __restrict__ g, int E, const int* __restrict__ off,
                              const int* __restrict__ keep, const int* __restrict__ pos,
                              int* __restrict__ cursor, int* __restrict__ csrv,
                              u64* __restrict__ subbits, float* __restrict__ invdeg) {
    __shared__ int nb[320];
    __shared__ int nbcnt;
    __shared__ int cntS;
    __shared__ u64 accLDS[64];
    int bid = blockIdx.x;
    int t = threadIdx.x;
    if (bid >= MP) {
        int e = (bid - MP) * 256 + t;
        if (e < E) {
            int s = g[e], dd = g[E + e];
            int p = atomicAdd(&cursor[s], 1);
            csrv[off[s] + p] = keep[dd] ? pos[dd] : -1;
        }
        return;
    }
    int r = bid;
    int wv = t >> 6, lane = t & 63;
    if (r >= KKEEP) {
        if (t < SUBW) subbits[(size_t)r * SUBW + t] = 0;
        return;
    }
    int i = idxl[r];
    if (wv == 0) {
        u64 rw = rowbits[(size_t)i * 64 + lane];
        int myc = __popcll(rw);
        int pre = myc;
        #pragma unroll
        for (int s2 = 1; s2 < 64; s2 <<= 1) {
            int tt = __shfl_up(pre, s2);
            if (lane >= s2) pre += tt;
        }
        pre -= myc;
        u64 w = rw; int j = 0;
        while (w) {
            int b = __builtin_ctzll(w);
            w &= w - 1;
            nb[pre + j] = lane * 64 + b; ++j;
        }
        if (lane == 63) nbcnt = pre + myc;
    } else if (wv == 1) {
        accLDS[lane] = 0;
    } else if (wv == 2 && lane == 0) {
        cntS = 0;
    }
    __syncthreads();
    int cnt_nb = nbcnt;
    u64 accw = 0;
    for (int j = wv; j < cnt_nb; j += 4)
        accw |= rowbits[(size_t)nb[j] * 64 + lane];
    atomicOr(&accLDS[lane], accw);
    __syncthreads();
    // projection: register copy + shfl (no random LDS reads)
    u64 accw_full = accLDS[lane];
    int cntp = 0;
    #pragma unroll
    for (int wjj = 0; wjj < 10; ++wjj) {
        int wj = wv * 10 + wjj;
        int c = wj * 64 + lane;
        int ci = (c < KKEEP) ? idxl[c] : 0;
        u64 w = __shfl(accw_full, ci >> 6);
        int bit = (c < KKEEP) ? (int)((w >> (ci & 63)) & 1ull) : 0;
        u64 word = __ballot(bit);
        cntp += __popcll(word);
        if (lane == 0) subbits[(size_t)r * SUBW + wj] = word;
    }
    if (lane == 0) atomicAdd(&cntS, cntp);
    __syncthreads();
    if (t == 0) invdeg[r] = 1.0f / (float)cntS;
}

// t'[c] = (h0[idx[c]]*scores[idx[c]]) @ W2 * invdeg[c], transposed bf16 [DD][KP]
__global__ void k_t(const float* __restrict__ h0, const float* __restrict__ scores,
                    const int* __restrict__ idxl, const float* __restrict__ W2,
                    const float* __restrict__ invdeg, ushort_t* __restrict__ tT) {
    __shared__ float rows[RT][DD];
    int d = threadIdx.x;
    int r0 = blockIdx.x * RT;
    #pragma unroll
    for (int r = 0; r < RT; ++r) {
        int rr = r0 + r;
        float v = 0.f;
        if (rr < KKEEP) {
            int i = idxl[rr];
            v = h0[(size_t)i * DD + d] * scores[i];
        }
        rows[r][d] = v;
    }
    __syncthreads();
    float acc[RT];
    #pragma unroll
    for (int r = 0; r < RT; ++r) acc[r] = 0.f;
    for (int kb = 0; kb < DD; kb += 16) {
        float w[16];
        #pragma unroll
        for (int j = 0; j < 16; ++j) w[j] = W2[(size_t)(kb + j) * DD + d];
        #pragma unroll
        for (int r = 0; r < RT; ++r)
            #pragma unroll
            for (int j = 0; j < 16; ++j) acc[r] += rows[r][kb + j] * w[j];
    }
    bf16x8 packed;
    #pragma unroll
    for (int r = 0; r < RT; ++r) {
        int rr = r0 + r;
        float v = (rr < KKEEP) ? acc[r] * invdeg[rr] : 0.f;
        __hip_bfloat16 b = __float2bfloat16(v);
        packed[r] = *reinterpret_cast<short*>(&b);
    }
    *reinterpret_cast<bf16x8*>(tT + (size_t)d * KP + r0) = packed;
}

// uu = S @ t' + cu, with A-fragments expanded from subbits via LDS LUT.
// Block per 16x16 tile, 4 waves split-K, LDS reduce. XCD-swizzled tiles.
__global__ void k_gemm(const u64* __restrict__ subbits, const short* __restrict__ tT,
                       const float* __restrict__ cu, float* __restrict__ uu) {
    __shared__ f32x4 red[4][64];
    __shared__ uint4 lut[256];
    int t = threadIdx.x;
    {   // byte -> 8 bf16 (4 u32 pairs): bit j -> element j (1.0f bf16 = 0x3F80)
        uint32_t x0 = ((t & 1) ? 0x3F80u : 0u) | ((t & 2) ? 0x3F800000u : 0u);
        uint32_t x1 = ((t & 4) ? 0x3F80u : 0u) | ((t & 8) ? 0x3F800000u : 0u);
        uint32_t x2 = ((t & 16) ? 0x3F80u : 0u) | ((t & 32) ? 0x3F800000u : 0u);
        uint32_t x3 = ((t & 64) ? 0x3F80u : 0u) | ((t & 128) ? 0x3F800000u : 0u);
        lut[t] = make_uint4(x0, x1, x2, x3);
    }
    __syncthreads();
    int bid = blockIdx.x;
    int tile = (bid & 7) * (MT * NT / 8) + (bid >> 3);   // bijective: 1232=8*154
    int wv = t >> 6, lane = t & 63;
    int rt = tile >> 3, ct = tile & 7;
    const u64* abits = subbits + (size_t)(rt * 16 + (lane & 15)) * SUBW;
    const short* brow = tT + (size_t)(ct * 16 + (lane & 15)) * KP + ((lane >> 4) * 8) + wv * KCHUNK;
    int kbase = wv * KCHUNK + ((lane >> 4) * 8);
    f32x4 acc = {0.f, 0.f, 0.f, 0.f};
    #pragma unroll 4
    for (int kk = 0; kk < KCHUNK; kk += 32) {
        int k = kbase + kk;
        u64 w = abits[k >> 6];
        int byte = (int)((w >> (k & 63)) & 0xFFull);
        uint4 af = lut[byte];
        bf16x8 a = *reinterpret_cast<bf16x8*>(&af);
        bf16x8 b = *(const bf16x8*)(brow + kk);
        acc = __builtin_amdgcn_mfma_f32_16x16x32_bf16(a, b, acc, 0, 0, 0);
    }
    red[wv][lane] = acc;
    __syncthreads();
    if (wv == 0) {
        f32x4 s = red[0][lane] + red[1][lane] + red[2][lane] + red[3][lane];
        int col = ct * 16 + (lane & 15);
        float cuv = cu[col];
        int row0 = rt * 16 + ((lane >> 4) * 4);
        #pragma unroll
        for (int j = 0; j < 4; ++j) {
            int row = row0 + j;
            if (row < KKEEP) uu[(size_t)row * DD + col] = s[j] + cuv;
        }
    }
}

__global__ void k_agg(const int* __restrict__ off, const int* __restrict__ csrv,
                      const float* __restrict__ uu, const float* __restrict__ bu,
                      const float* __restrict__ h0, const float* __restrict__ h,
                      float* __restrict__ out) {
    int s = blockIdx.x, d = threadIdx.x;
    int b = off[s], e2 = off[s + 1];
    float acc = 0.f;
    int k = b;
    for (; k + 4 <= e2; k += 4) {
        int v0 = csrv[k], v1 = csrv[k + 1], v2 = csrv[k + 2], v3 = csrv[k + 3];
        float a0 = (v0 >= 0) ? uu[(size_t)v0 * DD + d] : 0.f;
        float a1 = (v1 >= 0) ? uu[(size_t)v1 * DD + d] : 0.f;
        float a2 = (v2 >= 0) ? uu[(size_t)v2 * DD + d] : 0.f;
        float a3 = (v3 >= 0) ? uu[(size_t)v3 * DD + d] : 0.f;
        acc += (a0 + a1) + (a2 + a3);
    }
    for (; k < e2; ++k) {
        int v = csrv[k];
        if (v >= 0) acc += uu[(size_t)v * DD + d];
    }
    size_t o = (size_t)s * DD + d;
    float a = acc + bu[d] + h0[o];
    out[o] = a;
    out[(size_t)NN * DD + o] = a + h[o];
}

extern "C" void kernel_launch(void* const* d_in, const int* in_sizes, int n_in,
                              void* d_out, int out_size, void* d_ws, size_t ws_size,
                              hipStream_t stream) {
    const int*   g  = (const int*)d_in[0];
    const float* h  = (const float*)d_in[1];
    const float* Wd = (const float*)d_in[2];
    const float* bd = (const float*)d_in[3];
    const float* pw = (const float*)d_in[4];
    const float* pb = (const float*)d_in[5];
    const float* Wb = (const float*)d_in[6];
    const float* bb = (const float*)d_in[7];
    const float* Wu = (const float*)d_in[8];
    const float* bu = (const float*)d_in[9];
    float* out = (float*)d_out;
    int E = in_sizes[0] / 2;

    char* ws = (char*)d_ws;
    u64*      subbits = (u64*)  (ws + 0);                  // 788 KB
    u64*      rowbits = (u64*)  (ws + (13u << 20));        // 2 MB
    int*      deg     = (int*)  (ws + (15u << 20));        // 16 KB
    int*      cursor  = (int*)  (ws + (15u << 20) + 16384);
    int*      off     = (int*)  (ws + (15u << 20) + 32768);
    float*    h0      = (float*)(ws + (16u << 20));        // 2 MB
    ushort_t* tT      = (ushort_t*)(ws + (18u << 20));     // 656 KB
    int*      csrv    = (int*)  (ws + (21u << 20));        // 512 KB
    float*    uu      = (float*)(ws + (22u << 20));        // 1.26 MB
    float*    scores  = (float*)(ws + (24u << 20));
    float*    invdeg  = (float*)(ws + (24u << 20) + 16384);
    int*      pos     = (int*)  (ws + (24u << 20) + 32768);
    int*      keep    = (int*)  (ws + (24u << 20) + 49152);
    int*      idxl    = (int*)  (ws + (24u << 20) + 65536);
    float*    W2      = (float*)(ws + (24u << 20) + 98304); // 64 KB
    float*    cu      = (float*)(ws + (24u << 20) + 98304 + 65536);

    k_zero<<<520, 256, 0, stream>>>((float4*)rowbits);
    k_h0_build<<<1553, 128, 0, stream>>>(h, Wd, bd, pw, pb, g, E, Wb, Wu, bb,
                                         h0, scores, rowbits, deg, W2, cu);
    k_rank_scan<<<NN / 4 + 1, 256, 0, stream>>>(scores, deg, keep, pos, idxl, off);
    k_sub_scatter<<<MP + E / 256, 256, 0, stream>>>(rowbits, idxl, g, E, off,
                                                    keep, pos, cursor, csrv, subbits, invdeg);
    k_t<<<KP / RT, DD, 0, stream>>>(h0, scores, idxl, W2, invdeg, tT);
    k_gemm<<<MT * NT, 256, 0, stream>>>(subbits, (const short*)tT, cu, uu);
    k_agg<<<NN, DD, 0, stream>>>(off, csrv, uu, bu, h0, h, out);
}